// Round 1
// baseline (598.163 us; speedup 1.0000x reference)
//
#include <hip/hip_runtime.h>
#include <math.h>

// StatefulRosenberg R8: fused single-pass decoupled-aggregate scan.
//
// R7 counters: k_emit FETCH was only ~66 MB (f0 re-read served by LLC),
// 2.8 TB/s, VALUBusy 21%, occ 53% -> latency/structure bound, and pass 1
// (k_chunk_sums) existed only to produce 32 KB of chunk sums from a full
// 67 MB f0 read. R8 fuses both passes:
//   - each block computes its chunk aggregate from the f0 it already
//     loaded, publishes it (device-scope release flag), THEN waits
//     wave-parallel for all <=255 predecessor aggregates.
//   - publish-before-wait => no serial lookback chain; waits bounded by
//     one publish latency, not a 256-deep dependency.
//   - ticket-ordered virtual block ids => a spinning block only ever
//     waits on lower-ticket (already started) blocks => no deadlock
//     regardless of dispatch order (Guideline 16).
//   - nontemporal loads/stores: every line of f0/oq/wav touched once.
// Numerics identical to R7 (f64 scan infrastructure, f32 per-element
// accumulation after a single f64 wrap; oq loaded AFTER the scan -- R6
// showed pre-scan hoist spills).

constexpr int BATCH   = 16;
constexpr int T       = 1048576;
constexpr int THREADS = 256;
constexpr int VPT     = 16;               // elements per thread
constexpr int CHUNK   = THREADS * VPT;    // 4096
constexpr int NCHUNK  = T / CHUNK;        // 256
constexpr int NBLK    = BATCH * NCHUNK;   // 4096

#define INV_SR (1.0f / 48000.0f)

typedef float v4f __attribute__((ext_vector_type(4)));

__global__ __launch_bounds__(THREADS, 8) void k_fused(
    const float* __restrict__ f0, const float* __restrict__ oq,
    const float* __restrict__ phase_state,
    float* __restrict__ wav, float* __restrict__ next_state,
    double* __restrict__ partial, unsigned int* __restrict__ flags,
    unsigned int* __restrict__ ticket)
{
    __shared__ double rs[THREADS / 64];   // chunk-prefix partial reduce
    __shared__ double ws[THREADS / 64];   // wave inclusive totals
    __shared__ unsigned int stk;

    // ---- ticket: virtual block id, monotone with scheduling order ----
    if (threadIdx.x == 0) stk = atomicAdd(ticket, 1u);
    __syncthreads();
    const int vbid  = (int)stk;
    const int row   = vbid & (BATCH - 1);   // interleave rows for even progress
    const int chunk = vbid / BATCH;
    const int lane  = threadIdx.x & 63, wid = threadIdx.x >> 6;
    const size_t base_idx = (size_t)row * T + (size_t)chunk * CHUNK
                          + (size_t)threadIdx.x * VPT;
    const int slot = row * NCHUNK + chunk;

    // ---- pre-scan loads ----
    const v4f* fb = (const v4f*)(f0 + base_idx);
    v4f f_0 = __builtin_nontemporal_load(fb + 0);
    v4f f_1 = __builtin_nontemporal_load(fb + 1);
    v4f f_2 = __builtin_nontemporal_load(fb + 2);
    v4f f_3 = __builtin_nontemporal_load(fb + 3);
    const float pstate = phase_state[row];

    // ---- f32 steps (match ref rounding scale) + thread fp64 sum ----
    float st[VPT];
    st[ 0]=f_0.x*INV_SR; st[ 1]=f_0.y*INV_SR; st[ 2]=f_0.z*INV_SR; st[ 3]=f_0.w*INV_SR;
    st[ 4]=f_1.x*INV_SR; st[ 5]=f_1.y*INV_SR; st[ 6]=f_1.z*INV_SR; st[ 7]=f_1.w*INV_SR;
    st[ 8]=f_2.x*INV_SR; st[ 9]=f_2.y*INV_SR; st[10]=f_2.z*INV_SR; st[11]=f_2.w*INV_SR;
    st[12]=f_3.x*INV_SR; st[13]=f_3.y*INV_SR; st[14]=f_3.z*INV_SR; st[15]=f_3.w*INV_SR;
    double tsum = 0.0;
#pragma unroll
    for (int i = 0; i < VPT; ++i) tsum += (double)st[i];

    // ---- block inclusive scan of per-thread sums (also yields totals) ----
    double inc = tsum;
#pragma unroll
    for (int off = 1; off < 64; off <<= 1) {
        double n = __shfl_up(inc, off, 64);
        if (lane >= off) inc += n;
    }
    if (lane == 63) ws[wid] = inc;
    __syncthreads();

    // ---- publish this chunk's aggregate (BEFORE any waiting) ----
    if (threadIdx.x == 0) {
        double tot = ws[0] + ws[1] + ws[2] + ws[3];
        __hip_atomic_store(&partial[slot], tot, __ATOMIC_RELAXED,
                           __HIP_MEMORY_SCOPE_AGENT);
        __hip_atomic_store(&flags[slot], 1u, __ATOMIC_RELEASE,
                           __HIP_MEMORY_SCOPE_AGENT);
    }

    // ---- wait for predecessor aggregates, wave-parallel (thread t -> chunk t) ----
    double pv = 0.0;
    if ((int)threadIdx.x < chunk) {
        const int p = row * NCHUNK + (int)threadIdx.x;
        unsigned int f = __hip_atomic_load(&flags[p], __ATOMIC_ACQUIRE,
                                           __HIP_MEMORY_SCOPE_AGENT);
        if (f == 0u) {
            int guard = 1 << 20;   // hang guard: bail to wrong-answer, never deadlock
            do {
                __builtin_amdgcn_s_sleep(2);
                f = __hip_atomic_load(&flags[p], __ATOMIC_ACQUIRE,
                                      __HIP_MEMORY_SCOPE_AGENT);
            } while (f == 0u && --guard);
        }
        pv = __hip_atomic_load(&partial[p], __ATOMIC_RELAXED,
                               __HIP_MEMORY_SCOPE_AGENT);
    }
#pragma unroll
    for (int off = 32; off > 0; off >>= 1)
        pv += __shfl_down(pv, off, 64);
    if (lane == 0) rs[wid] = pv;
    __syncthreads();

    const double chunkpref = rs[0] + rs[1] + rs[2] + rs[3];
    double run = (double)pstate + chunkpref + (inc - tsum);
#pragma unroll
    for (int w = 0; w < THREADS / 64; ++w)
        if (w < wid) run += ws[w];

    // next_state: unwrapped final phase, last chunk's thread 0
    if (chunk == NCHUNK - 1 && threadIdx.x == 0)
        next_state[row] = (float)((double)pstate + chunkpref
                                  + ws[0] + ws[1] + ws[2] + ws[3]);

    // wrap the thread base ONCE in f64; per-element accumulation is f32.
    float runf = (float)(run - floor(run));

    // ---- oq load AFTER the scan (pre-scan hoist spilled, R6) ----
    const v4f* ob = (const v4f*)(oq + base_idx);
    v4f o_0 = __builtin_nontemporal_load(ob + 0);
    v4f o_1 = __builtin_nontemporal_load(ob + 1);
    v4f o_2 = __builtin_nontemporal_load(ob + 2);
    v4f o_3 = __builtin_nontemporal_load(ob + 3);
    float o[VPT];
    o[ 0]=o_0.x; o[ 1]=o_0.y; o[ 2]=o_0.z; o[ 3]=o_0.w;
    o[ 4]=o_1.x; o[ 5]=o_1.y; o[ 6]=o_1.z; o[ 7]=o_1.w;
    o[ 8]=o_2.x; o[ 9]=o_2.y; o[10]=o_2.z; o[11]=o_2.w;
    o[12]=o_3.x; o[13]=o_3.y; o[14]=o_3.z; o[15]=o_3.w;

    // ---- accumulate + pulse; one v_cos per element, arg in revolutions ----
    float outv[VPT];
#pragma unroll
    for (int i = 0; i < VPT; ++i) {
        runf += st[i];
        float ph  = __builtin_amdgcn_fractf(runf);   // wrapped phase in [0,1)
        float oqv = o[i];
        float tp  = oqv * 0.66f;
        bool  is_rise  = ph < tp;
        bool  in_pulse = ph < oqv;
        float num = is_rise ? ph : (ph - tp);
        float den = is_rise ? fmaf(oqv, 0.66f, 1e-6f)    // tp + eps
                            : fmaf(oqv, 0.68f, 1e-6f);   // 2*tn + eps
        // cos(pi * num/den) == v_cos(0.5 * num/den revolutions)
        float rev = 0.5f * num * __builtin_amdgcn_rcpf(den);
        float c   = __builtin_amdgcn_cosf(rev);
        outv[i] = is_rise ? 0.5f * (1.0f - c) : (in_pulse ? c : 0.0f);
    }

    v4f* wb = (v4f*)(wav + base_idx);
#pragma unroll
    for (int j = 0; j < VPT / 4; ++j) {
        v4f vv;
        vv.x = outv[4 * j + 0]; vv.y = outv[4 * j + 1];
        vv.z = outv[4 * j + 2]; vv.w = outv[4 * j + 3];
        __builtin_nontemporal_store(vv, wb + j);
    }
}

extern "C" void kernel_launch(void* const* d_in, const int* in_sizes, int n_in,
                              void* d_out, int out_size, void* d_ws, size_t ws_size,
                              hipStream_t stream)
{
    const float* f0          = (const float*)d_in[0];
    const float* oq          = (const float*)d_in[1];
    const float* phase_state = (const float*)d_in[2];
    float* out = (float*)d_out;                 // [B*T] wav, then [B] next_state

    // workspace layout: partial (4096 f64 = 32 KB) | flags (4096 u32 = 16 KB) | ticket (4 B)
    double*       partial = (double*)d_ws;
    unsigned int* flags   = (unsigned int*)((char*)d_ws + NBLK * sizeof(double));
    unsigned int* ticket  = flags + NBLK;

    // zero flags + ticket (stream-ordered, graph-capture legal)
    hipMemsetAsync((char*)d_ws + NBLK * sizeof(double), 0,
                   NBLK * sizeof(unsigned int) + sizeof(unsigned int), stream);

    k_fused<<<NBLK, THREADS, 0, stream>>>(f0, oq, phase_state,
                                          out, out + (size_t)BATCH * T,
                                          partial, flags, ticket);
}

// Round 2
// 192.189 us; speedup vs baseline: 3.1124x; 3.1124x over previous
//
#include <hip/hip_runtime.h>
#include <math.h>

// StatefulRosenberg R9: revert to two-pass (R7 structure, 178 us) + oq hoist.
//
// R8 post-mortem: fused decoupled-aggregate scan was 9x WORSE (470 us,
// VALUBusy 2.7%) -- acquire-scope spin loops emit vmcnt(0)+cache-invalidate
// per poll; 2048 resident blocks polling = fabric thrash. Reverted.
//
// R9 change vs R7: R6's "oq hoist spills" was a register-CAP artifact:
// __launch_bounds__(256,8) caps the allocator at 512/8=64 VGPRs. With
// (256,4) the cap is 128 and the hoist fits. Measured occupancy was 53%
// anyway, so guaranteeing 4 blocks/CU (50%) instead of 8 loses nothing,
// while the oq load latency now hides under the f64 scan instead of being
// serially exposed after it.
//   - k_emit: __launch_bounds__(256,4); f0+oq+partial+pstate ALL loaded
//     before the scan; oq nontemporal (read-once), wav store nontemporal
//     (keep LLC for f0, which pass 2 re-reads from LLC -- R7 FETCH showed
//     only ~66 MB because of this; do NOT mark f0 nontemporal).
//   - k_chunk_sums unchanged.
// Numerics identical to R7: f64 scan infrastructure, f32 per-element
// accumulation after one f64 wrap (max unwrapped 1.0003 -> single fract).

constexpr int BATCH   = 16;
constexpr int T       = 1048576;
constexpr int THREADS = 256;
constexpr int VPT     = 16;               // elements per thread
constexpr int CHUNK   = THREADS * VPT;    // 4096
constexpr int NCHUNK  = T / CHUNK;        // 256

#define INV_SR (1.0f / 48000.0f)

typedef float v4f __attribute__((ext_vector_type(4)));

// ---------------- Pass 1: per-chunk fp64 sums ----------------
__global__ __launch_bounds__(THREADS, 8) void k_chunk_sums(
    const float* __restrict__ f0, double* __restrict__ partial)
{
    const int chunk = blockIdx.x;
    const int row   = blockIdx.y;
    const v4f* base = (const v4f*)(f0 + (size_t)row * T
                     + (size_t)chunk * CHUNK + (size_t)threadIdx.x * VPT);
    v4f v0 = base[0], v1 = base[1], v2 = base[2], v3 = base[3];
    double s = 0.0;
    s += (double)(v0.x * INV_SR) + (double)(v0.y * INV_SR)
       + (double)(v0.z * INV_SR) + (double)(v0.w * INV_SR);
    s += (double)(v1.x * INV_SR) + (double)(v1.y * INV_SR)
       + (double)(v1.z * INV_SR) + (double)(v1.w * INV_SR);
    s += (double)(v2.x * INV_SR) + (double)(v2.y * INV_SR)
       + (double)(v2.z * INV_SR) + (double)(v2.w * INV_SR);
    s += (double)(v3.x * INV_SR) + (double)(v3.y * INV_SR)
       + (double)(v3.z * INV_SR) + (double)(v3.w * INV_SR);
#pragma unroll
    for (int off = 32; off > 0; off >>= 1)
        s += __shfl_down(s, off, 64);
    __shared__ double ws[THREADS / 64];
    const int lane = threadIdx.x & 63, wid = threadIdx.x >> 6;
    if (lane == 0) ws[wid] = s;
    __syncthreads();
    if (threadIdx.x == 0)
        partial[row * NCHUNK + chunk] = ws[0] + ws[1] + ws[2] + ws[3];
}

// ---------------- Pass 2: prefix + intra-chunk scan + Rosenberg pulse ----------------
__global__ __launch_bounds__(THREADS, 4) void k_emit(
    const float* __restrict__ f0, const float* __restrict__ oq,
    const double* __restrict__ partial, const float* __restrict__ phase_state,
    float* __restrict__ wav, float* __restrict__ next_state)
{
    const int chunk = blockIdx.x;
    const int row   = blockIdx.y;
    const int lane  = threadIdx.x & 63, wid = threadIdx.x >> 6;
    const size_t base_idx = (size_t)row * T + (size_t)chunk * CHUNK
                          + (size_t)threadIdx.x * VPT;

    __shared__ double rs[THREADS / 64];   // chunk-prefix partial reduce
    __shared__ double ws[THREADS / 64];   // wave inclusive totals

    // ---- ALL global loads issued before the scan (latency hides under it) ----
    const v4f* fb = (const v4f*)(f0 + base_idx);
    v4f f_0 = fb[0], f_1 = fb[1], f_2 = fb[2], f_3 = fb[3];
    const v4f* ob = (const v4f*)(oq + base_idx);
    v4f o_0 = __builtin_nontemporal_load(ob + 0);
    v4f o_1 = __builtin_nontemporal_load(ob + 1);
    v4f o_2 = __builtin_nontemporal_load(ob + 2);
    v4f o_3 = __builtin_nontemporal_load(ob + 3);
    double pv = (threadIdx.x < chunk) ? partial[row * NCHUNK + threadIdx.x] : 0.0;
    const float pstate = phase_state[row];

    // ---- f32 steps (match ref rounding scale) + thread fp64 sum ----
    float st[VPT];
    st[ 0]=f_0.x*INV_SR; st[ 1]=f_0.y*INV_SR; st[ 2]=f_0.z*INV_SR; st[ 3]=f_0.w*INV_SR;
    st[ 4]=f_1.x*INV_SR; st[ 5]=f_1.y*INV_SR; st[ 6]=f_1.z*INV_SR; st[ 7]=f_1.w*INV_SR;
    st[ 8]=f_2.x*INV_SR; st[ 9]=f_2.y*INV_SR; st[10]=f_2.z*INV_SR; st[11]=f_2.w*INV_SR;
    st[12]=f_3.x*INV_SR; st[13]=f_3.y*INV_SR; st[14]=f_3.z*INV_SR; st[15]=f_3.w*INV_SR;
    double tsum = 0.0;
#pragma unroll
    for (int i = 0; i < VPT; ++i) tsum += (double)st[i];

    // ---- chunk prefix: parallel reduce of partial[row][0..chunk-1] (L2-hot) ----
#pragma unroll
    for (int off = 32; off > 0; off >>= 1)
        pv += __shfl_down(pv, off, 64);
    if (lane == 0) rs[wid] = pv;

    // ---- block exclusive scan of per-thread sums ----
    double inc = tsum;
#pragma unroll
    for (int off = 1; off < 64; off <<= 1) {
        double n = __shfl_up(inc, off, 64);
        if (lane >= off) inc += n;
    }
    if (lane == 63) ws[wid] = inc;
    __syncthreads();

    const double chunkpref = rs[0] + rs[1] + rs[2] + rs[3];
    double run = (double)pstate + chunkpref + (inc - tsum);
#pragma unroll
    for (int w = 0; w < THREADS / 64; ++w)
        if (w < wid) run += ws[w];

    // next_state: unwrapped final phase, written by the last chunk's thread 0
    if (chunk == NCHUNK - 1 && threadIdx.x == 0)
        next_state[row] = (float)((double)pstate + chunkpref
                                  + ws[0] + ws[1] + ws[2] + ws[3]);

    // wrap the thread base ONCE in f64; per-element accumulation is f32.
    // max unwrapped value < 1 + 16*(1/48000) -> single fract suffices.
    float runf = (float)(run - floor(run));

    float o[VPT];
    o[ 0]=o_0.x; o[ 1]=o_0.y; o[ 2]=o_0.z; o[ 3]=o_0.w;
    o[ 4]=o_1.x; o[ 5]=o_1.y; o[ 6]=o_1.z; o[ 7]=o_1.w;
    o[ 8]=o_2.x; o[ 9]=o_2.y; o[10]=o_2.z; o[11]=o_2.w;
    o[12]=o_3.x; o[13]=o_3.y; o[14]=o_3.z; o[15]=o_3.w;

    // ---- accumulate + pulse; one v_cos per element, arg in revolutions ----
    float outv[VPT];
#pragma unroll
    for (int i = 0; i < VPT; ++i) {
        runf += st[i];
        float ph  = __builtin_amdgcn_fractf(runf);   // wrapped phase in [0,1)
        float oqv = o[i];
        float tp  = oqv * 0.66f;
        bool  is_rise  = ph < tp;
        bool  in_pulse = ph < oqv;
        float num = is_rise ? ph : (ph - tp);
        float den = is_rise ? fmaf(oqv, 0.66f, 1e-6f)    // tp + eps
                            : fmaf(oqv, 0.68f, 1e-6f);   // 2*tn + eps
        // cos(pi * num/den) == v_cos(0.5 * num/den revolutions)
        float rev = 0.5f * num * __builtin_amdgcn_rcpf(den);
        float c   = __builtin_amdgcn_cosf(rev);
        outv[i] = is_rise ? 0.5f * (1.0f - c) : (in_pulse ? c : 0.0f);
    }

    v4f* wb = (v4f*)(wav + base_idx);
#pragma unroll
    for (int j = 0; j < VPT / 4; ++j) {
        v4f vv;
        vv.x = outv[4 * j + 0]; vv.y = outv[4 * j + 1];
        vv.z = outv[4 * j + 2]; vv.w = outv[4 * j + 3];
        __builtin_nontemporal_store(vv, wb + j);
    }
}

extern "C" void kernel_launch(void* const* d_in, const int* in_sizes, int n_in,
                              void* d_out, int out_size, void* d_ws, size_t ws_size,
                              hipStream_t stream)
{
    const float* f0          = (const float*)d_in[0];
    const float* oq          = (const float*)d_in[1];
    const float* phase_state = (const float*)d_in[2];
    float* out = (float*)d_out;                 // [B*T] wav, then [B] next_state

    double* partial = (double*)d_ws;            // B*NCHUNK doubles (32 KB)

    dim3 grid(NCHUNK, BATCH);
    k_chunk_sums<<<grid, THREADS, 0, stream>>>(f0, partial);
    k_emit<<<grid, THREADS, 0, stream>>>(f0, oq, partial, phase_state,
                                         out, out + (size_t)BATCH * T);
}

// Round 3
// 183.460 us; speedup vs baseline: 3.2605x; 1.0476x over previous
//
#include <hip/hip_runtime.h>
#include <math.h>

// StatefulRosenberg R10: R9 minus the nontemporal wav store.
//
// R9 post-mortem (counters):
//   - oq hoist WORKED: effective BW 2.84 -> 3.1 TB/s (latency hidden
//     under the f64 scan). Keep it, keep __launch_bounds__(256,4).
//   - nontemporal wav store BACKFIRED: WRITE_SIZE 65.5 -> 94-97 MB.
//     Each store instr writes 16B/lane at 64B stride (partial lines);
//     without nt, L2 merges the 4 partials into full 128B lines
//     (R7 WRITE was exactly 65540 KB). With nt the no-allocate hint
//     streams partial lines -> HBM write amplification (+30 MB = +7 us).
//     Removed. nt LOADS on oq kept (read-once, FETCH unchanged).
// Numerics identical: f64 scan infrastructure, f32 per-element
// accumulation after one f64 wrap (max unwrapped 1.0003 -> one fract).

constexpr int BATCH   = 16;
constexpr int T       = 1048576;
constexpr int THREADS = 256;
constexpr int VPT     = 16;               // elements per thread
constexpr int CHUNK   = THREADS * VPT;    // 4096
constexpr int NCHUNK  = T / CHUNK;        // 256

#define INV_SR (1.0f / 48000.0f)

typedef float v4f __attribute__((ext_vector_type(4)));

// ---------------- Pass 1: per-chunk fp64 sums ----------------
__global__ __launch_bounds__(THREADS, 8) void k_chunk_sums(
    const float* __restrict__ f0, double* __restrict__ partial)
{
    const int chunk = blockIdx.x;
    const int row   = blockIdx.y;
    const v4f* base = (const v4f*)(f0 + (size_t)row * T
                     + (size_t)chunk * CHUNK + (size_t)threadIdx.x * VPT);
    v4f v0 = base[0], v1 = base[1], v2 = base[2], v3 = base[3];
    double s = 0.0;
    s += (double)(v0.x * INV_SR) + (double)(v0.y * INV_SR)
       + (double)(v0.z * INV_SR) + (double)(v0.w * INV_SR);
    s += (double)(v1.x * INV_SR) + (double)(v1.y * INV_SR)
       + (double)(v1.z * INV_SR) + (double)(v1.w * INV_SR);
    s += (double)(v2.x * INV_SR) + (double)(v2.y * INV_SR)
       + (double)(v2.z * INV_SR) + (double)(v2.w * INV_SR);
    s += (double)(v3.x * INV_SR) + (double)(v3.y * INV_SR)
       + (double)(v3.z * INV_SR) + (double)(v3.w * INV_SR);
#pragma unroll
    for (int off = 32; off > 0; off >>= 1)
        s += __shfl_down(s, off, 64);
    __shared__ double ws[THREADS / 64];
    const int lane = threadIdx.x & 63, wid = threadIdx.x >> 6;
    if (lane == 0) ws[wid] = s;
    __syncthreads();
    if (threadIdx.x == 0)
        partial[row * NCHUNK + chunk] = ws[0] + ws[1] + ws[2] + ws[3];
}

// ---------------- Pass 2: prefix + intra-chunk scan + Rosenberg pulse ----------------
__global__ __launch_bounds__(THREADS, 4) void k_emit(
    const float* __restrict__ f0, const float* __restrict__ oq,
    const double* __restrict__ partial, const float* __restrict__ phase_state,
    float* __restrict__ wav, float* __restrict__ next_state)
{
    const int chunk = blockIdx.x;
    const int row   = blockIdx.y;
    const int lane  = threadIdx.x & 63, wid = threadIdx.x >> 6;
    const size_t base_idx = (size_t)row * T + (size_t)chunk * CHUNK
                          + (size_t)threadIdx.x * VPT;

    __shared__ double rs[THREADS / 64];   // chunk-prefix partial reduce
    __shared__ double ws[THREADS / 64];   // wave inclusive totals

    // ---- ALL global loads issued before the scan (latency hides under it) ----
    const v4f* fb = (const v4f*)(f0 + base_idx);
    v4f f_0 = fb[0], f_1 = fb[1], f_2 = fb[2], f_3 = fb[3];
    const v4f* ob = (const v4f*)(oq + base_idx);
    v4f o_0 = __builtin_nontemporal_load(ob + 0);
    v4f o_1 = __builtin_nontemporal_load(ob + 1);
    v4f o_2 = __builtin_nontemporal_load(ob + 2);
    v4f o_3 = __builtin_nontemporal_load(ob + 3);
    double pv = (threadIdx.x < chunk) ? partial[row * NCHUNK + threadIdx.x] : 0.0;
    const float pstate = phase_state[row];

    // ---- f32 steps (match ref rounding scale) + thread fp64 sum ----
    float st[VPT];
    st[ 0]=f_0.x*INV_SR; st[ 1]=f_0.y*INV_SR; st[ 2]=f_0.z*INV_SR; st[ 3]=f_0.w*INV_SR;
    st[ 4]=f_1.x*INV_SR; st[ 5]=f_1.y*INV_SR; st[ 6]=f_1.z*INV_SR; st[ 7]=f_1.w*INV_SR;
    st[ 8]=f_2.x*INV_SR; st[ 9]=f_2.y*INV_SR; st[10]=f_2.z*INV_SR; st[11]=f_2.w*INV_SR;
    st[12]=f_3.x*INV_SR; st[13]=f_3.y*INV_SR; st[14]=f_3.z*INV_SR; st[15]=f_3.w*INV_SR;
    double tsum = 0.0;
#pragma unroll
    for (int i = 0; i < VPT; ++i) tsum += (double)st[i];

    // ---- chunk prefix: parallel reduce of partial[row][0..chunk-1] (L2-hot) ----
#pragma unroll
    for (int off = 32; off > 0; off >>= 1)
        pv += __shfl_down(pv, off, 64);
    if (lane == 0) rs[wid] = pv;

    // ---- block exclusive scan of per-thread sums ----
    double inc = tsum;
#pragma unroll
    for (int off = 1; off < 64; off <<= 1) {
        double n = __shfl_up(inc, off, 64);
        if (lane >= off) inc += n;
    }
    if (lane == 63) ws[wid] = inc;
    __syncthreads();

    const double chunkpref = rs[0] + rs[1] + rs[2] + rs[3];
    double run = (double)pstate + chunkpref + (inc - tsum);
#pragma unroll
    for (int w = 0; w < THREADS / 64; ++w)
        if (w < wid) run += ws[w];

    // next_state: unwrapped final phase, written by the last chunk's thread 0
    if (chunk == NCHUNK - 1 && threadIdx.x == 0)
        next_state[row] = (float)((double)pstate + chunkpref
                                  + ws[0] + ws[1] + ws[2] + ws[3]);

    // wrap the thread base ONCE in f64; per-element accumulation is f32.
    // max unwrapped value < 1 + 16*(1/48000) -> single fract suffices.
    float runf = (float)(run - floor(run));

    float o[VPT];
    o[ 0]=o_0.x; o[ 1]=o_0.y; o[ 2]=o_0.z; o[ 3]=o_0.w;
    o[ 4]=o_1.x; o[ 5]=o_1.y; o[ 6]=o_1.z; o[ 7]=o_1.w;
    o[ 8]=o_2.x; o[ 9]=o_2.y; o[10]=o_2.z; o[11]=o_2.w;
    o[12]=o_3.x; o[13]=o_3.y; o[14]=o_3.z; o[15]=o_3.w;

    // ---- accumulate + pulse; one v_cos per element, arg in revolutions ----
    float outv[VPT];
#pragma unroll
    for (int i = 0; i < VPT; ++i) {
        runf += st[i];
        float ph  = __builtin_amdgcn_fractf(runf);   // wrapped phase in [0,1)
        float oqv = o[i];
        float tp  = oqv * 0.66f;
        bool  is_rise  = ph < tp;
        bool  in_pulse = ph < oqv;
        float num = is_rise ? ph : (ph - tp);
        float den = is_rise ? fmaf(oqv, 0.66f, 1e-6f)    // tp + eps
                            : fmaf(oqv, 0.68f, 1e-6f);   // 2*tn + eps
        // cos(pi * num/den) == v_cos(0.5 * num/den revolutions)
        float rev = 0.5f * num * __builtin_amdgcn_rcpf(den);
        float c   = __builtin_amdgcn_cosf(rev);
        outv[i] = is_rise ? 0.5f * (1.0f - c) : (in_pulse ? c : 0.0f);
    }

    v4f* wb = (v4f*)(wav + base_idx);
#pragma unroll
    for (int j = 0; j < VPT / 4; ++j) {
        v4f vv;
        vv.x = outv[4 * j + 0]; vv.y = outv[4 * j + 1];
        vv.z = outv[4 * j + 2]; vv.w = outv[4 * j + 3];
        wb[j] = vv;   // regular store: let L2 merge partial lines (R9 lesson)
    }
}

extern "C" void kernel_launch(void* const* d_in, const int* in_sizes, int n_in,
                              void* d_out, int out_size, void* d_ws, size_t ws_size,
                              hipStream_t stream)
{
    const float* f0          = (const float*)d_in[0];
    const float* oq          = (const float*)d_in[1];
    const float* phase_state = (const float*)d_in[2];
    float* out = (float*)d_out;                 // [B*T] wav, then [B] next_state

    double* partial = (double*)d_ws;            // B*NCHUNK doubles (32 KB)

    dim3 grid(NCHUNK, BATCH);
    k_chunk_sums<<<grid, THREADS, 0, stream>>>(f0, partial);
    k_emit<<<grid, THREADS, 0, stream>>>(f0, oq, partial, phase_state,
                                         out, out + (size_t)BATCH * T);
}

// Round 4
// 174.809 us; speedup vs baseline: 3.4218x; 1.0495x over previous
//
#include <hip/hip_runtime.h>
#include <math.h>

// StatefulRosenberg R11: occupancy push — VPT 16->8, 8 blocks/CU.
//
// R10 counters: k_emit 45 us, 3.04 TB/s (48% of achievable), VALUBusy 23%,
// occupancy 50% (bounds(256,4) caps 4 blocks/CU). Wave lifetime = load
// burst -> stall -> ~2000 cyc compute (mem pipe idle) -> store burst;
// at 16 waves/CU the idle-compute phases leave the memory pipe ~half fed.
// R11: VPT=8 cuts live state to ~48 VGPR -> fits the 64-VGPR cap of
// __launch_bounds__(256,8) -> 32 waves/CU -> loads of some waves overlap
// compute of others. CHUNK=2048, NCHUNK=512 (chunk-prefix reduce takes two
// L2-hot partial loads per thread). tsum tree-summed (shorter f64 chain).
// Watch item: spill signature = FETCH/WRITE moving off 68.5/65.5 MB (R6).
//
// Kept from earlier rounds: oq hoisted pre-scan (R9: +0.25 TB/s), regular
// wav store (R9: nt-store caused +30 MB write amplification), nt loads on
// oq only, f64 scan infra + f32 per-element accumulation (one f64 wrap).

constexpr int BATCH   = 16;
constexpr int T       = 1048576;
constexpr int THREADS = 256;
constexpr int VPT     = 8;                // elements per thread
constexpr int CHUNK   = THREADS * VPT;    // 2048
constexpr int NCHUNK  = T / CHUNK;        // 512

#define INV_SR (1.0f / 48000.0f)

typedef float v4f __attribute__((ext_vector_type(4)));

// ---------------- Pass 1: per-chunk fp64 sums ----------------
__global__ __launch_bounds__(THREADS, 8) void k_chunk_sums(
    const float* __restrict__ f0, double* __restrict__ partial)
{
    const int chunk = blockIdx.x;
    const int row   = blockIdx.y;
    const v4f* base = (const v4f*)(f0 + (size_t)row * T
                     + (size_t)chunk * CHUNK + (size_t)threadIdx.x * VPT);
    v4f v0 = base[0], v1 = base[1];
    double s = ((double)(v0.x * INV_SR) + (double)(v0.y * INV_SR))
             + ((double)(v0.z * INV_SR) + (double)(v0.w * INV_SR))
             + ((double)(v1.x * INV_SR) + (double)(v1.y * INV_SR))
             + ((double)(v1.z * INV_SR) + (double)(v1.w * INV_SR));
#pragma unroll
    for (int off = 32; off > 0; off >>= 1)
        s += __shfl_down(s, off, 64);
    __shared__ double ws[THREADS / 64];
    const int lane = threadIdx.x & 63, wid = threadIdx.x >> 6;
    if (lane == 0) ws[wid] = s;
    __syncthreads();
    if (threadIdx.x == 0)
        partial[row * NCHUNK + chunk] = ws[0] + ws[1] + ws[2] + ws[3];
}

// ---------------- Pass 2: prefix + intra-chunk scan + Rosenberg pulse ----------------
__global__ __launch_bounds__(THREADS, 8) void k_emit(
    const float* __restrict__ f0, const float* __restrict__ oq,
    const double* __restrict__ partial, const float* __restrict__ phase_state,
    float* __restrict__ wav, float* __restrict__ next_state)
{
    const int chunk = blockIdx.x;
    const int row   = blockIdx.y;
    const int lane  = threadIdx.x & 63, wid = threadIdx.x >> 6;
    const size_t base_idx = (size_t)row * T + (size_t)chunk * CHUNK
                          + (size_t)threadIdx.x * VPT;

    __shared__ double rs[THREADS / 64];   // chunk-prefix partial reduce
    __shared__ double ws[THREADS / 64];   // wave inclusive totals

    // ---- ALL global loads issued before the scan (latency hides under it) ----
    const v4f* fb = (const v4f*)(f0 + base_idx);
    v4f f_0 = fb[0], f_1 = fb[1];
    const v4f* ob = (const v4f*)(oq + base_idx);
    v4f o_0 = __builtin_nontemporal_load(ob + 0);
    v4f o_1 = __builtin_nontemporal_load(ob + 1);
    // chunk-prefix inputs: up to 512 partials, two L2-hot loads per thread
    double pv = 0.0;
    if ((int)threadIdx.x < chunk)       pv  = partial[row * NCHUNK + threadIdx.x];
    if ((int)threadIdx.x + 256 < chunk) pv += partial[row * NCHUNK + threadIdx.x + 256];
    const float pstate = phase_state[row];

    // ---- f32 steps (match ref rounding scale) + thread fp64 sum (tree) ----
    float st[VPT];
    st[0]=f_0.x*INV_SR; st[1]=f_0.y*INV_SR; st[2]=f_0.z*INV_SR; st[3]=f_0.w*INV_SR;
    st[4]=f_1.x*INV_SR; st[5]=f_1.y*INV_SR; st[6]=f_1.z*INV_SR; st[7]=f_1.w*INV_SR;
    double tsum = (((double)st[0] + (double)st[1]) + ((double)st[2] + (double)st[3]))
                + (((double)st[4] + (double)st[5]) + ((double)st[6] + (double)st[7]));

    // ---- chunk prefix: parallel reduce (L2-hot) ----
#pragma unroll
    for (int off = 32; off > 0; off >>= 1)
        pv += __shfl_down(pv, off, 64);
    if (lane == 0) rs[wid] = pv;

    // ---- block exclusive scan of per-thread sums ----
    double inc = tsum;
#pragma unroll
    for (int off = 1; off < 64; off <<= 1) {
        double n = __shfl_up(inc, off, 64);
        if (lane >= off) inc += n;
    }
    if (lane == 63) ws[wid] = inc;
    __syncthreads();

    const double chunkpref = rs[0] + rs[1] + rs[2] + rs[3];
    double run = (double)pstate + chunkpref + (inc - tsum);
#pragma unroll
    for (int w = 0; w < THREADS / 64; ++w)
        if (w < wid) run += ws[w];

    // next_state: unwrapped final phase, written by the last chunk's thread 0
    if (chunk == NCHUNK - 1 && threadIdx.x == 0)
        next_state[row] = (float)((double)pstate + chunkpref
                                  + ws[0] + ws[1] + ws[2] + ws[3]);

    // wrap the thread base ONCE in f64; per-element accumulation is f32.
    // max unwrapped value < 1 + 8*(1/48000) -> single fract suffices.
    float runf = (float)(run - floor(run));

    float o[VPT];
    o[0]=o_0.x; o[1]=o_0.y; o[2]=o_0.z; o[3]=o_0.w;
    o[4]=o_1.x; o[5]=o_1.y; o[6]=o_1.z; o[7]=o_1.w;

    // ---- accumulate + pulse; one v_cos per element, arg in revolutions ----
    float outv[VPT];
#pragma unroll
    for (int i = 0; i < VPT; ++i) {
        runf += st[i];
        float ph  = __builtin_amdgcn_fractf(runf);   // wrapped phase in [0,1)
        float oqv = o[i];
        float tp  = oqv * 0.66f;
        bool  is_rise  = ph < tp;
        bool  in_pulse = ph < oqv;
        float num = is_rise ? ph : (ph - tp);
        float den = is_rise ? fmaf(oqv, 0.66f, 1e-6f)    // tp + eps
                            : fmaf(oqv, 0.68f, 1e-6f);   // 2*tn + eps
        // cos(pi * num/den) == v_cos(0.5 * num/den revolutions)
        float rev = 0.5f * num * __builtin_amdgcn_rcpf(den);
        float c   = __builtin_amdgcn_cosf(rev);
        outv[i] = is_rise ? 0.5f * (1.0f - c) : (in_pulse ? c : 0.0f);
    }

    v4f* wb = (v4f*)(wav + base_idx);
#pragma unroll
    for (int j = 0; j < VPT / 4; ++j) {
        v4f vv;
        vv.x = outv[4 * j + 0]; vv.y = outv[4 * j + 1];
        vv.z = outv[4 * j + 2]; vv.w = outv[4 * j + 3];
        wb[j] = vv;   // regular store: let L2 merge partial lines (R9 lesson)
    }
}

extern "C" void kernel_launch(void* const* d_in, const int* in_sizes, int n_in,
                              void* d_out, int out_size, void* d_ws, size_t ws_size,
                              hipStream_t stream)
{
    const float* f0          = (const float*)d_in[0];
    const float* oq          = (const float*)d_in[1];
    const float* phase_state = (const float*)d_in[2];
    float* out = (float*)d_out;                 // [B*T] wav, then [B] next_state

    double* partial = (double*)d_ws;            // B*NCHUNK doubles (64 KB)

    dim3 grid(NCHUNK, BATCH);
    k_chunk_sums<<<grid, THREADS, 0, stream>>>(f0, partial);
    k_emit<<<grid, THREADS, 0, stream>>>(f0, oq, partial, phase_state,
                                         out, out + (size_t)BATCH * T);
}